// Round 10
// baseline (248.005 us; speedup 1.0000x reference)
//
#include <hip/hip_runtime.h>
#include <math.h>

#define BGR 8
#define NN 2048
#define KNN 4
#define INCH 16
#define HID 128
#define CL 64
#define NE 262144
#define NT (BGR*NN)   // 16384

// workspace layout (float offsets)
#define OFF_DEG   0            // 16384 (float deg)
#define OFF_AGG1  16384        // 262144
#define OFF_H1    278528       // 2097152 (h1; read by mega — do NOT alias partials here)
#define OFF_NBR   2375680      // 65536 (ints)
#define OFF_AGG2  2441216      // 2097152 (part_ss)
#define OFF_H2    4538368      // 2097152 (h2 eliminated -> part_pool lives here)
#define OFF_TR    6733824      // 8
#define OFF_CA    6733832      // 512
#define OFF_SSUM  6734344      // 512
#define OFF_MS    6734856      // 8

// zero deg+agg1 (contiguous 278528) + tr/ca/ssum/msum (1040) + loss
__global__ void k_init(float* ws, float* small, float* loss) {
  int i = blockIdx.x * 256 + threadIdx.x;
  if (i < 278528) ws[i] = 0.f;
  int j = i - 278528;
  if (j >= 0 && j < 1040) small[j] = 0.f;
  if (i == 0) loss[0] = 0.f;
}

// in-degree histogram over original edges (also = adj.sum(1) for dmon)
__global__ void k_deg(const int* __restrict__ dst, float* __restrict__ deg) {
  int e = blockIdx.x * 256 + threadIdx.x;
  if (e < NE) atomicAdd(&deg[dst[e]], 1.0f);
}

// scatter x[src]*dis[src] into agg1[dst] (16 channels, linearity of GCN)
__global__ void k_scatter1(const int* __restrict__ src, const int* __restrict__ dst,
                           const float* __restrict__ x, const float* __restrict__ deg,
                           float* __restrict__ agg1) {
  int t = blockIdx.x * 256 + threadIdx.x;
  int e = t >> 4, c = t & 15;
  if (e >= NE) return;
  int s = src[e], d = dst[e];
  float ds = 1.0f / sqrtf(deg[s] + 1.0f);
  atomicAdd(&agg1[d * INCH + c], x[s * INCH + c] * ds);
}

// h1 = relu( ((agg1 + x*dis)*dis) @ W1 + b1 )
__global__ __launch_bounds__(128) void k_gemm1(const float* __restrict__ agg1,
    const float* __restrict__ x, const float* __restrict__ deg,
    const float* __restrict__ W1, const float* __restrict__ b1, float* __restrict__ h1) {
  __shared__ float a1[INCH];
  int n = blockIdx.x, j = threadIdx.x;
  if (j < INCH) {
    float dn = 1.0f / sqrtf(deg[n] + 1.0f);
    a1[j] = (agg1[n * INCH + j] + x[n * INCH + j] * dn) * dn;
  }
  __syncthreads();
  float acc = b1[j];
#pragma unroll
  for (int c = 0; c < INCH; c++) acc += a1[c] * W1[c * HID + j];
  h1[(size_t)n * HID + j] = fmaxf(acc, 0.f);
}

// kNN k=4 per graph on h1[:, :3]. 1024-thread blocks, 2 rows/wave.
// Packed u32 keys (d2 bits | slot), 7-op min/max network; unroll-4 only
// (full unroll spills 25MB scratch — R7 post-mortem).
__global__ __launch_bounds__(1024) void k_knn(const float* __restrict__ h1, int* __restrict__ nbr) {
  __shared__ float4 c4[NN];   // 32KB
  int g = blockIdx.y, tid = threadIdx.x;
  for (int i = tid; i < NN; i += 1024)
    c4[i] = *(const float4*)(h1 + (size_t)(g * NN + i) * HID);
  __syncthreads();
  int wid = tid >> 6, lane = tid & 63;
  int row0 = blockIdx.x * 32 + wid * 2;
  float mx[2], my[2], mz[2];
#pragma unroll
  for (int r = 0; r < 2; r++) { float4 m = c4[row0 + r]; mx[r] = m.x; my[r] = m.y; mz[r] = m.z; }
  unsigned t0[2], t1[2], t2[2], t3[2];
#pragma unroll
  for (int r = 0; r < 2; r++) { t0[r] = t1[r] = t2[r] = t3[r] = 0xFFFFFFFFu; }
#pragma unroll 4
  for (int i = 0; i < 32; i++) {
    int j = i * 64 + lane;
    float4 p = c4[j];
#pragma unroll
    for (int r = 0; r < 2; r++) {
      float dx = p.x - mx[r], dy = p.y - my[r], dz = p.z - mz[r];
      float d2 = dx * dx + dy * dy + dz * dz;
      unsigned k = (__float_as_uint(d2) & 0xFFFFFFE0u) | (unsigned)i;
      if (j == row0 + r) k = 0xFFFFFFFFu;   // exclude self
      unsigned M0 = max(t0[r], k); t0[r] = min(t0[r], k);
      unsigned M1 = max(t1[r], M0); t1[r] = min(t1[r], M0);
      unsigned M2 = max(t2[r], M1); t2[r] = min(t2[r], M1);
      t3[r] = min(t3[r], M2);
    }
  }
#pragma unroll
  for (int r = 0; r < 2; r++) {
    unsigned a0 = t0[r], a1 = t1[r], a2 = t2[r], a3 = t3[r];
    int res[4];
#pragma unroll
    for (int k = 0; k < 4; k++) {
      int cj = (int)((a0 & 31u) << 6) | lane;
      unsigned wd = a0; int wj = cj;
#pragma unroll
      for (int off = 32; off; off >>= 1) {
        unsigned od = (unsigned)__shfl_xor((int)wd, off, 64);
        int oj = __shfl_xor(wj, off, 64);
        bool take = (od < wd) || (od == wd && oj < wj);
        wd = take ? od : wd; wj = take ? oj : wj;
      }
      res[k] = wj;
      bool pop = (cj == wj);
      a0 = pop ? a1 : a0; a1 = pop ? a2 : a1; a2 = pop ? a3 : a2;
      a3 = pop ? 0xFFFFFFFFu : a3;
    }
    if (lane == 0) {
      int node = g * NN + row0 + r;
      ((int4*)nbr)[node] = make_int4(g * NN + res[0], g * NN + res[1],
                                     g * NN + res[2], g * NN + res[3]);
    }
  }
}

// MEGA: gather+GEMM2 (h2 stays in LDS) -> softmax s -> DMoN pool/ss partials.
// grid 256 blocks x 256 threads; block = one 64-node slice (b = blk>>5, sl = blk&31).
__global__ __launch_bounds__(256) void k_mega(const float* __restrict__ h1,
    const int* __restrict__ nbr, const float* __restrict__ W2,
    const float* __restrict__ b2, const float* __restrict__ Wp,
    const float* __restrict__ bp, const float* __restrict__ deg,
    float* __restrict__ s_out, float* __restrict__ part_pool,
    float* __restrict__ part_ss, float* __restrict__ ca,
    float* __restrict__ ssum, float* __restrict__ msum) {
  __shared__ float At[64][17];     // 4.25KB
  __shared__ float Bt[16 * 128];   // 8KB
  __shared__ float ht[64 * 128];   // 32KB  (h2 tile, post-relu)
  __shared__ float st[64 * 64];    // 16KB  (s tile)
  __shared__ float red[256];
  __shared__ float dt[64];
  int tid = threadIdx.x;
  int rbase = blockIdx.x * 64;
  // Wp column cache in registers (lane c = tid&63; 4 threads share column)
  int lane = tid & 63, wq = tid >> 6;
  float w[HID];
#pragma unroll
  for (int k = 0; k < HID; k++) w[k] = Wp[k * CL + lane];
  float bpv = bp[lane];
  if (tid < 64) dt[tid] = deg[rbase + tid];
  // ---- phase A: GEMM2 with on-the-fly neighbor gather ----
  int r = tid >> 2, q = tid & 3;
  int4 nb = ((const int4*)nbr)[rbase + r];
  const float4* h4 = (const float4*)h1;
  size_t r0 = (size_t)(rbase + r) * 32, rx = (size_t)nb.x * 32, ry = (size_t)nb.y * 32,
         rz = (size_t)nb.z * 32, rw = (size_t)nb.w * 32;
  int rg = tid >> 5;            // 0..7 -> rows rg*8..+8
  int cg = (tid & 31) * 4;      // cols
  float acc[8][4];
#pragma unroll
  for (int i = 0; i < 8; i++)
#pragma unroll
    for (int j = 0; j < 4; j++) acc[i][j] = 0.f;
  for (int k0 = 0; k0 < HID; k0 += 16) {
    {
      int q4 = (k0 >> 2) + q;
      float4 a = h4[r0 + q4], bx = h4[rx + q4], by = h4[ry + q4],
             bz = h4[rz + q4], bw = h4[rw + q4];
      int kk = q * 4;
      At[r][kk]     = (a.x + bx.x + by.x + bz.x + bw.x) * 0.2f;
      At[r][kk + 1] = (a.y + bx.y + by.y + bz.y + bw.y) * 0.2f;
      At[r][kk + 2] = (a.z + bx.z + by.z + bz.z + bw.z) * 0.2f;
      At[r][kk + 3] = (a.w + bx.w + by.w + bz.w + bw.w) * 0.2f;
    }
    {
      int kk = tid >> 5;
      int cc = (tid & 31) * 4;
      *(float4*)&Bt[kk * 128 + cc] = *(const float4*)&W2[(k0 + kk) * HID + cc];
      *(float4*)&Bt[(kk + 8) * 128 + cc] = *(const float4*)&W2[(k0 + kk + 8) * HID + cc];
    }
    __syncthreads();
#pragma unroll
    for (int kk = 0; kk < 16; kk++) {
      float4 bv = *(const float4*)&Bt[kk * 128 + cg];
#pragma unroll
      for (int i = 0; i < 8; i++) {
        float av = At[rg * 8 + i][kk];
        acc[i][0] += av * bv.x; acc[i][1] += av * bv.y;
        acc[i][2] += av * bv.z; acc[i][3] += av * bv.w;
      }
    }
    __syncthreads();
  }
  // ---- phase B: bias+relu into LDS h2 tile (no global h2) ----
#pragma unroll
  for (int i = 0; i < 8; i++) {
#pragma unroll
    for (int j = 0; j < 4; j++)
      ht[(rg * 8 + i) * 128 + cg + j] = fmaxf(acc[i][j] + b2[cg + j], 0.f);
  }
  __syncthreads();
  // ---- phase C: s = softmax(h2 @ Wp + bp); wave wq covers rows wq,wq+4,... ----
  for (int n = wq; n < 64; n += 4) {
    const float4* hp = (const float4*)&ht[n * 128];
    float a2 = bpv;
#pragma unroll
    for (int k4 = 0; k4 < 32; k4++) {
      float4 h = hp[k4];   // broadcast across lanes
      a2 += h.x * w[k4 * 4] + h.y * w[k4 * 4 + 1] + h.z * w[k4 * 4 + 2] + h.w * w[k4 * 4 + 3];
    }
    float m = a2;
    for (int off = 32; off; off >>= 1) m = fmaxf(m, __shfl_xor(m, off, 64));
    float e = expf(a2 - m);
    float sum = e;
    for (int off = 32; off; off >>= 1) sum += __shfl_xor(sum, off, 64);
    float sv = e / sum;
    st[n * 64 + lane] = sv;
    s_out[(size_t)(rbase + n) * CL + lane] = sv;
  }
  __syncthreads();
  // ---- phase D: pool/ss partials + small reductions ----
  int b = blockIdx.x >> 5, sl = blockIdx.x & 31;
  int c = lane;
  int fg = wq * 32;
  float pacc[32];
#pragma unroll
  for (int i = 0; i < 32; i++) pacc[i] = 0.f;
  for (int n = 0; n < 64; n++) {
    float a = st[n * 64 + c];
#pragma unroll
    for (int i = 0; i < 32; i++) pacc[i] += a * ht[n * 128 + fg + i];
  }
  float* pp = part_pool + ((size_t)(b * 32 + sl)) * 8192 + c * 128 + fg;
#pragma unroll
  for (int i = 0; i < 32; i += 4)
    *(float4*)&pp[i] = make_float4(pacc[i], pacc[i + 1], pacc[i + 2], pacc[i + 3]);
  int dg = wq * 16;
  float sacc[16];
#pragma unroll
  for (int i = 0; i < 16; i++) sacc[i] = 0.f;
  for (int n = 0; n < 64; n++) {
    float a = st[n * 64 + c];
#pragma unroll
    for (int i = 0; i < 16; i++) sacc[i] += a * st[n * 64 + dg + i];
  }
  float* ps = part_ss + ((size_t)(b * 32 + sl)) * 4096 + c * 64 + dg;
#pragma unroll
  for (int i = 0; i < 16; i += 4)
    *(float4*)&ps[i] = make_float4(sacc[i], sacc[i + 1], sacc[i + 2], sacc[i + 3]);
  float a_ss = 0, a_ca = 0, a_m = 0;
  for (int n = wq; n < 64; n += 4) {
    float sv = st[n * 64 + c];
    float dv = dt[n];
    a_ss += sv; a_ca += sv * dv;
    if (c == 0) a_m += dv;
  }
  red[tid] = a_ss; __syncthreads();
  if (wq == 0) atomicAdd(&ssum[b * CL + c], red[c] + red[64 + c] + red[128 + c] + red[192 + c]);
  __syncthreads();
  red[tid] = a_ca; __syncthreads();
  if (wq == 0) atomicAdd(&ca[b * CL + c], red[c] + red[64 + c] + red[128 + c] + red[192 + c]);
  __syncthreads();
  red[tid] = (c == 0) ? a_m : 0.f; __syncthreads();
  if (tid == 0) atomicAdd(&msum[b], red[0] + red[64] + red[128] + red[192]);
}

// trace(s^T A s) per graph = sum over edges of dot(s[src], s[dst]).
__global__ __launch_bounds__(256) void k_trace(const int* __restrict__ src,
    const int* __restrict__ dst, const float* __restrict__ s, float* __restrict__ tr) {
  __shared__ float bins[8];
  int tid = threadIdx.x;
  if (tid < 8) bins[tid] = 0.f;
  __syncthreads();
  int sub = tid & 15;
  int grp = (blockIdx.x * 256 + tid) >> 4;   // 8192 groups
  const float4* s4 = (const float4*)s;
  for (int e = grp; e < NE; e += 8192) {
    int se = src[e], de = dst[e];
    float4 a = s4[se * 16 + sub];
    float4 b = s4[de * 16 + sub];
    float v = a.x * b.x + a.y * b.y + a.z * b.z + a.w * b.w;
    v += __shfl_xor(v, 1, 64);
    v += __shfl_xor(v, 2, 64);
    v += __shfl_xor(v, 4, 64);
    v += __shfl_xor(v, 8, 64);
    if (sub == 0) atomicAdd(&bins[se >> 11], v);
  }
  __syncthreads();
  if (tid < 8) atomicAdd(&tr[tid], bins[tid]);
}

// fused epilogue: blocks 0..255 = pool-fold + selu + log_softmax (2 rows/blk);
// blocks 256..263 = per-graph scalar loss.
__global__ __launch_bounds__(256) void k_final(const float* __restrict__ part_pool,
    const float* __restrict__ part_ss, const float* __restrict__ ca,
    const float* __restrict__ ssum, const float* __restrict__ msum,
    const float* __restrict__ tr, float* __restrict__ out, float* __restrict__ outs) {
  int tid = threadIdx.x;
  if (blockIdx.x < 256) {
    __shared__ float r[4], r2[4];
    int half = tid >> 7, f = tid & 127;
    int row = blockIdx.x * 2 + half;
    int wid = tid >> 6;
    const float* p = part_pool + (size_t)(row >> 6) * 32 * 8192 + (row & 63) * 128 + f;
    float v = 0.f;
#pragma unroll
    for (int sl = 0; sl < 32; sl++) v += p[sl * 8192];
    const float scale = 1.0507009873554805f, alpha = 1.6732632423543772f;
    v = scale * (v > 0.f ? v : alpha * expm1f(v));
    float m = v;
    for (int off = 32; off; off >>= 1) m = fmaxf(m, __shfl_xor(m, off, 64));
    if ((tid & 63) == 0) r[wid] = m;
    __syncthreads();
    m = fmaxf(r[half * 2], r[half * 2 + 1]);
    float e = expf(v - m);
    float sum = e;
    for (int off = 32; off; off >>= 1) sum += __shfl_xor(sum, off, 64);
    if ((tid & 63) == 0) r2[wid] = sum;
    __syncthreads();
    sum = r2[half * 2] + r2[half * 2 + 1];
    out[(size_t)row * HID + f] = v - m - logf(sum);
  } else {
    __shared__ float ssb[4096];
    __shared__ float red[256];
    int b = blockIdx.x - 256;
    float loc = 0.f;
    for (int idx = tid; idx < 4096; idx += 256) {
      const float* p = part_ss + (size_t)b * 32 * 4096 + idx;
      float v = 0.f;
#pragma unroll
      for (int sl = 0; sl < 32; sl++) v += p[sl * 4096];
      ssb[idx] = v;
      loc += v * v;
    }
    red[tid] = loc; __syncthreads();
    for (int s2 = 128; s2; s2 >>= 1) { if (tid < s2) red[tid] += red[tid + s2]; __syncthreads(); }
    float fro = sqrtf(red[0]);
    __syncthreads();
    loc = 0.f;
    for (int i = tid; i < 4096; i += 256) {
      float v = ssb[i] / fro - (((i % 65) == 0) ? 0.125f : 0.f);
      loc += v * v;
    }
    red[tid] = loc; __syncthreads();
    for (int s2 = 128; s2; s2 >>= 1) { if (tid < s2) red[tid] += red[tid + s2]; __syncthreads(); }
    float ortho_b = sqrtf(red[0]);
    __syncthreads();
    loc = 0.f;
    if (tid < 64) { float v = ca[b * 64 + tid]; loc = v * v; }
    red[tid] = loc; __syncthreads();
    for (int s2 = 128; s2; s2 >>= 1) { if (tid < s2) red[tid] += red[tid + s2]; __syncthreads(); }
    float caSq = red[0];
    __syncthreads();
    loc = 0.f;
    if (tid < 64) { float v = ssum[b * 64 + tid]; loc = v * v; }
    red[tid] = loc; __syncthreads();
    for (int s2 = 128; s2; s2 >>= 1) { if (tid < s2) red[tid] += red[tid + s2]; __syncthreads(); }
    float ssumSq = red[0];
    __syncthreads();
    if (tid == 0) {
      float m2 = msum[b];                       // = 2*m
      float spectral_b = -(tr[b] - caSq / m2) / m2;
      float cluster_b = sqrtf(ssumSq) / 2048.0f * 8.0f - 1.0f;
      atomicAdd(&outs[0], (spectral_b + ortho_b + cluster_b) * 0.125f);
    }
  }
}

extern "C" void kernel_launch(void* const* d_in, const int* in_sizes, int n_in,
                              void* d_out, int out_size, void* d_ws, size_t ws_size,
                              hipStream_t stream) {
  (void)in_sizes; (void)n_in; (void)out_size; (void)ws_size;
  const float* x   = (const float*)d_in[0];
  const int* esrc  = (const int*)d_in[1];
  const int* edst  = (const int*)d_in[2];
  const float* W1  = (const float*)d_in[4];
  const float* b1  = (const float*)d_in[5];
  const float* W2  = (const float*)d_in[6];
  const float* b2  = (const float*)d_in[7];
  const float* Wp  = (const float*)d_in[8];
  const float* bp  = (const float*)d_in[9];
  float* out = (float*)d_out;
  float* ws  = (float*)d_ws;

  float* deg   = ws + OFF_DEG;
  float* agg1  = ws + OFF_AGG1;
  float* h1    = ws + OFF_H1;
  int*   nbr   = (int*)(ws + OFF_NBR);
  float* tr    = ws + OFF_TR;
  float* ca    = ws + OFF_CA;
  float* ssum  = ws + OFF_SSUM;
  float* msum  = ws + OFF_MS;
  float* part_pool = ws + OFF_H2;    // h2 never materialized; region reused
  float* part_ss   = ws + OFF_AGG2;
  float* s_out = out + 65537;   // chunk 2: s [8,2048,64]

  k_init<<<1093, 256, 0, stream>>>(ws, ws + OFF_TR, out + 65536);
  k_deg<<<NE / 256, 256, 0, stream>>>(edst, deg);
  k_scatter1<<<NE * 16 / 256, 256, 0, stream>>>(esrc, edst, x, deg, agg1);
  k_gemm1<<<NT, 128, 0, stream>>>(agg1, x, deg, W1, b1, h1);
  k_knn<<<dim3(64, 8), 1024, 0, stream>>>(h1, nbr);
  k_mega<<<256, 256, 0, stream>>>(h1, nbr, W2, b2, Wp, bp, deg, s_out,
                                  part_pool, part_ss, ca, ssum, msum);
  k_trace<<<512, 256, 0, stream>>>(esrc, edst, s_out, tr);
  k_final<<<264, 256, 0, stream>>>(part_pool, part_ss, ca, ssum, msum, tr,
                                   out, out + 65536);
}

// Round 11
// 237.502 us; speedup vs baseline: 1.0442x; 1.0442x over previous
//
#include <hip/hip_runtime.h>
#include <math.h>

#define BGR 8
#define NN 2048
#define KNN 4
#define INCH 16
#define HID 128
#define CL 64
#define NE 262144
#define NT (BGR*NN)   // 16384

// workspace layout (float offsets)
#define OFF_DEG   0            // 16384 (float deg)
#define OFF_AGG1  16384        // 262144
#define OFF_H1    278528       // 2097152  (reused as part_pool after gemm2f)
#define OFF_NBR   2375680      // 65536 (ints)
#define OFF_AGG2  2441216      // 2097152  (part_ss)
#define OFF_H2    4538368      // 2097152
#define OFF_TR    6733824      // 8
#define OFF_CA    6733832      // 512
#define OFF_SSUM  6734344      // 512
#define OFF_MS    6734856      // 8

// zero deg+agg1 (contiguous 278528) + tr/ca/ssum/msum (1040) + loss
__global__ void k_init(float* ws, float* small, float* loss) {
  int i = blockIdx.x * 256 + threadIdx.x;
  if (i < 278528) ws[i] = 0.f;
  int j = i - 278528;
  if (j >= 0 && j < 1040) small[j] = 0.f;
  if (i == 0) loss[0] = 0.f;
}

// in-degree histogram over original edges (also = adj.sum(1) for dmon)
__global__ void k_deg(const int* __restrict__ dst, float* __restrict__ deg) {
  int e = blockIdx.x * 256 + threadIdx.x;
  if (e < NE) atomicAdd(&deg[dst[e]], 1.0f);
}

// scatter x[src]*dis[src] into agg1[dst] (16 channels, linearity of GCN)
__global__ void k_scatter1(const int* __restrict__ src, const int* __restrict__ dst,
                           const float* __restrict__ x, const float* __restrict__ deg,
                           float* __restrict__ agg1) {
  int t = blockIdx.x * 256 + threadIdx.x;
  int e = t >> 4, c = t & 15;
  if (e >= NE) return;
  int s = src[e], d = dst[e];
  float ds = 1.0f / sqrtf(deg[s] + 1.0f);
  atomicAdd(&agg1[d * INCH + c], x[s * INCH + c] * ds);
}

// h1 = relu( ((agg1 + x*dis)*dis) @ W1 + b1 )
__global__ __launch_bounds__(128) void k_gemm1(const float* __restrict__ agg1,
    const float* __restrict__ x, const float* __restrict__ deg,
    const float* __restrict__ W1, const float* __restrict__ b1, float* __restrict__ h1) {
  __shared__ float a1[INCH];
  int n = blockIdx.x, j = threadIdx.x;
  if (j < INCH) {
    float dn = 1.0f / sqrtf(deg[n] + 1.0f);
    a1[j] = (agg1[n * INCH + j] + x[n * INCH + j] * dn) * dn;
  }
  __syncthreads();
  float acc = b1[j];
#pragma unroll
  for (int c = 0; c < INCH; c++) acc += a1[c] * W1[c * HID + j];
  h1[(size_t)n * HID + j] = fmaxf(acc, 0.f);
}

// kNN k=4 per graph on h1[:, :3]. 1024-thread blocks, 2 rows/wave.
// Packed u32 keys (d2 bits | slot), 7-op min/max network; unroll-4 only
// (full unroll spills 25MB scratch — R7 post-mortem).
__global__ __launch_bounds__(1024) void k_knn(const float* __restrict__ h1, int* __restrict__ nbr) {
  __shared__ float4 c4[NN];   // 32KB
  int g = blockIdx.y, tid = threadIdx.x;
  for (int i = tid; i < NN; i += 1024)
    c4[i] = *(const float4*)(h1 + (size_t)(g * NN + i) * HID);
  __syncthreads();
  int wid = tid >> 6, lane = tid & 63;
  int row0 = blockIdx.x * 32 + wid * 2;
  float mx[2], my[2], mz[2];
#pragma unroll
  for (int r = 0; r < 2; r++) { float4 m = c4[row0 + r]; mx[r] = m.x; my[r] = m.y; mz[r] = m.z; }
  unsigned t0[2], t1[2], t2[2], t3[2];
#pragma unroll
  for (int r = 0; r < 2; r++) { t0[r] = t1[r] = t2[r] = t3[r] = 0xFFFFFFFFu; }
#pragma unroll 4
  for (int i = 0; i < 32; i++) {
    int j = i * 64 + lane;
    float4 p = c4[j];
#pragma unroll
    for (int r = 0; r < 2; r++) {
      float dx = p.x - mx[r], dy = p.y - my[r], dz = p.z - mz[r];
      float d2 = dx * dx + dy * dy + dz * dz;
      unsigned k = (__float_as_uint(d2) & 0xFFFFFFE0u) | (unsigned)i;
      if (j == row0 + r) k = 0xFFFFFFFFu;   // exclude self
      unsigned M0 = max(t0[r], k); t0[r] = min(t0[r], k);
      unsigned M1 = max(t1[r], M0); t1[r] = min(t1[r], M0);
      unsigned M2 = max(t2[r], M1); t2[r] = min(t2[r], M1);
      t3[r] = min(t3[r], M2);
    }
  }
#pragma unroll
  for (int r = 0; r < 2; r++) {
    unsigned a0 = t0[r], a1 = t1[r], a2 = t2[r], a3 = t3[r];
    int res[4];
#pragma unroll
    for (int k = 0; k < 4; k++) {
      int cj = (int)((a0 & 31u) << 6) | lane;
      unsigned wd = a0; int wj = cj;
#pragma unroll
      for (int off = 32; off; off >>= 1) {
        unsigned od = (unsigned)__shfl_xor((int)wd, off, 64);
        int oj = __shfl_xor(wj, off, 64);
        bool take = (od < wd) || (od == wd && oj < wj);
        wd = take ? od : wd; wj = take ? oj : wj;
      }
      res[k] = wj;
      bool pop = (cj == wj);
      a0 = pop ? a1 : a0; a1 = pop ? a2 : a1; a2 = pop ? a3 : a2;
      a3 = pop ? 0xFFFFFFFFu : a3;
    }
    if (lane == 0) {
      int node = g * NN + row0 + r;
      ((int4*)nbr)[node] = make_int4(g * NN + res[0], g * NN + res[1],
                                     g * NN + res[2], g * NN + res[3]);
    }
  }
}

// fused neighbor-gather + GEMM2: h2 = relu(((h1[n]+sum nbr h1)*0.2) @ W2 + b2)
__global__ __launch_bounds__(256) void k_gemm2f(const float* __restrict__ h1,
    const int* __restrict__ nbr, const float* __restrict__ W2,
    const float* __restrict__ b2, float* __restrict__ h2) {
  __shared__ float At[64][17];
  __shared__ float Bt[16 * 128];
  int tid = threadIdx.x;
  int rbase = blockIdx.x * 64;
  int r = tid >> 2, q = tid & 3;   // 4 threads per A-row, q = k-quad
  int4 nb = ((const int4*)nbr)[rbase + r];
  const float4* h4 = (const float4*)h1;
  size_t r0 = (size_t)(rbase + r) * 32, rx = (size_t)nb.x * 32, ry = (size_t)nb.y * 32,
         rz = (size_t)nb.z * 32, rw = (size_t)nb.w * 32;
  int rg = tid >> 5;            // 0..7 -> rows rg*8..+8
  int cg = (tid & 31) * 4;      // cols
  float acc[8][4];
#pragma unroll
  for (int i = 0; i < 8; i++)
#pragma unroll
    for (int j = 0; j < 4; j++) acc[i][j] = 0.f;
  for (int k0 = 0; k0 < HID; k0 += 16) {
    {
      int q4 = (k0 >> 2) + q;
      float4 a = h4[r0 + q4], bx = h4[rx + q4], by = h4[ry + q4],
             bz = h4[rz + q4], bw = h4[rw + q4];
      int kk = q * 4;
      At[r][kk]     = (a.x + bx.x + by.x + bz.x + bw.x) * 0.2f;
      At[r][kk + 1] = (a.y + bx.y + by.y + bz.y + bw.y) * 0.2f;
      At[r][kk + 2] = (a.z + bx.z + by.z + bz.z + bw.z) * 0.2f;
      At[r][kk + 3] = (a.w + bx.w + by.w + bz.w + bw.w) * 0.2f;
    }
    {
      int kk = tid >> 5;
      int cc = (tid & 31) * 4;
      *(float4*)&Bt[kk * 128 + cc] = *(const float4*)&W2[(k0 + kk) * HID + cc];
      *(float4*)&Bt[(kk + 8) * 128 + cc] = *(const float4*)&W2[(k0 + kk + 8) * HID + cc];
    }
    __syncthreads();
#pragma unroll
    for (int kk = 0; kk < 16; kk++) {
      float4 bv = *(const float4*)&Bt[kk * 128 + cg];
#pragma unroll
      for (int i = 0; i < 8; i++) {
        float av = At[rg * 8 + i][kk];
        acc[i][0] += av * bv.x; acc[i][1] += av * bv.y;
        acc[i][2] += av * bv.z; acc[i][3] += av * bv.w;
      }
    }
    __syncthreads();
  }
#pragma unroll
  for (int i = 0; i < 8; i++) {
    int rr = rbase + rg * 8 + i;
#pragma unroll
    for (int j = 0; j < 4; j++) {
      float v = acc[i][j] + b2[cg + j];
      h2[(size_t)rr * HID + cg + j] = fmaxf(v, 0.f);
    }
  }
}

// s = softmax(h2 @ Wp + bp) over C=64.
// Lane c register-caches Wp[:,c]; h2 row read as wave-uniform float4.
__global__ __launch_bounds__(256) void k_s(const float* __restrict__ h2,
    const float* __restrict__ Wp, const float* __restrict__ bp, float* __restrict__ s_out) {
  int tid = threadIdx.x, wid = tid >> 6, lane = tid & 63;
  float w[HID];
#pragma unroll
  for (int k = 0; k < HID; k++) w[k] = Wp[k * CL + lane];   // coalesced per k
  float bpv = bp[lane];
  int nbase = blockIdx.x * 32 + wid * 8;
  for (int u = 0; u < 8; u++) {
    int n = nbase + u;
    const float4* hp = (const float4*)(h2 + (size_t)n * HID);
    float acc = bpv;
#pragma unroll
    for (int k4 = 0; k4 < 32; k4++) {
      float4 h = hp[k4];
      acc += h.x * w[k4 * 4] + h.y * w[k4 * 4 + 1] + h.z * w[k4 * 4 + 2] + h.w * w[k4 * 4 + 3];
    }
    float m = acc;
    for (int off = 32; off; off >>= 1) m = fmaxf(m, __shfl_xor(m, off, 64));
    float e = expf(acc - m);
    float sum = e;
    for (int off = 32; off; off >>= 1) sum += __shfl_xor(sum, off, 64);
    s_out[(size_t)n * CL + lane] = e / sum;
  }
}

// fused: blocks 0..255 = DMoN tile reductions (pool/ss partials, plain
// stores; small ca/ssum/msum atomics); blocks 256..767 = edge trace.
__global__ __launch_bounds__(256) void k_dmon_trace(const float* __restrict__ s,
    const float* __restrict__ h2, const float* __restrict__ deg,
    float* __restrict__ part_pool, float* __restrict__ part_ss,
    float* __restrict__ ca, float* __restrict__ ssum, float* __restrict__ msum,
    const int* __restrict__ src, const int* __restrict__ dst, float* __restrict__ tr) {
  __shared__ float st[64 * 64];    // 16KB
  __shared__ float ht[64 * 128];   // 32KB
  __shared__ float dt[64];
  __shared__ float red[256];
  __shared__ float bins[8];
  int tid = threadIdx.x;
  if (blockIdx.x < 256) {
    int b = blockIdx.x >> 5, sl = blockIdx.x & 31;
    int nb = sl * 64;
    const float* sp = s + ((size_t)b * NN + nb) * CL;
    const float* hp = h2 + ((size_t)b * NN + nb) * HID;
    for (int i = tid; i < 64 * 64 / 4; i += 256) ((float4*)st)[i] = ((const float4*)sp)[i];
    for (int i = tid; i < 64 * 128 / 4; i += 256) ((float4*)ht)[i] = ((const float4*)hp)[i];
    if (tid < 64) dt[tid] = deg[b * NN + nb + tid];
    __syncthreads();
    int c = tid & 63;
    int fg = (tid >> 6) * 32;
    float acc[32];
#pragma unroll
    for (int i = 0; i < 32; i++) acc[i] = 0.f;
    for (int n = 0; n < 64; n++) {
      float a = st[n * 64 + c];
#pragma unroll
      for (int i = 0; i < 32; i++) acc[i] += a * ht[n * 128 + fg + i];
    }
    float* pp = part_pool + ((size_t)(b * 32 + sl)) * 8192 + c * 128 + fg;
#pragma unroll
    for (int i = 0; i < 32; i += 4)
      *(float4*)&pp[i] = make_float4(acc[i], acc[i + 1], acc[i + 2], acc[i + 3]);
    int dg = (tid >> 6) * 16;
    float sacc[16];
#pragma unroll
    for (int i = 0; i < 16; i++) sacc[i] = 0.f;
    for (int n = 0; n < 64; n++) {
      float a = st[n * 64 + c];
#pragma unroll
      for (int i = 0; i < 16; i++) sacc[i] += a * st[n * 64 + dg + i];
    }
    float* ps = part_ss + ((size_t)(b * 32 + sl)) * 4096 + c * 64 + dg;
#pragma unroll
    for (int i = 0; i < 16; i += 4)
      *(float4*)&ps[i] = make_float4(sacc[i], sacc[i + 1], sacc[i + 2], sacc[i + 3]);
    int q = tid >> 6;
    float a_ss = 0, a_ca = 0, a_m = 0;
    for (int n = q; n < 64; n += 4) {
      float sv = st[n * 64 + c];
      float dv = dt[n];
      a_ss += sv; a_ca += sv * dv;
      if (c == 0) a_m += dv;
    }
    red[tid] = a_ss; __syncthreads();
    if (q == 0) atomicAdd(&ssum[b * CL + c], red[c] + red[64 + c] + red[128 + c] + red[192 + c]);
    __syncthreads();
    red[tid] = a_ca; __syncthreads();
    if (q == 0) atomicAdd(&ca[b * CL + c], red[c] + red[64 + c] + red[128 + c] + red[192 + c]);
    __syncthreads();
    red[tid] = (c == 0) ? a_m : 0.f; __syncthreads();
    if (tid == 0) atomicAdd(&msum[b], red[0] + red[64] + red[128] + red[192]);
  } else {
    if (tid < 8) bins[tid] = 0.f;
    __syncthreads();
    int sub = tid & 15;
    int grp = ((blockIdx.x - 256) * 256 + tid) >> 4;   // 8192 groups
    const float4* s4 = (const float4*)s;
    for (int e = grp; e < NE; e += 8192) {
      int se = src[e], de = dst[e];
      float4 a = s4[se * 16 + sub];
      float4 b = s4[de * 16 + sub];
      float v = a.x * b.x + a.y * b.y + a.z * b.z + a.w * b.w;
      v += __shfl_xor(v, 1, 64);
      v += __shfl_xor(v, 2, 64);
      v += __shfl_xor(v, 4, 64);
      v += __shfl_xor(v, 8, 64);
      if (sub == 0) atomicAdd(&bins[se >> 11], v);
    }
    __syncthreads();
    if (tid < 8) atomicAdd(&tr[tid], bins[tid]);
  }
}

// fused epilogue: blocks 0..255 = pool-fold + selu + log_softmax (2 rows/blk);
// blocks 256..263 = per-graph scalar loss.
__global__ __launch_bounds__(256) void k_final(const float* __restrict__ part_pool,
    const float* __restrict__ part_ss, const float* __restrict__ ca,
    const float* __restrict__ ssum, const float* __restrict__ msum,
    const float* __restrict__ tr, float* __restrict__ out, float* __restrict__ outs) {
  int tid = threadIdx.x;
  if (blockIdx.x < 256) {
    __shared__ float r[4], r2[4];
    int half = tid >> 7, f = tid & 127;
    int row = blockIdx.x * 2 + half;
    int wid = tid >> 6;
    const float* p = part_pool + (size_t)(row >> 6) * 32 * 8192 + (row & 63) * 128 + f;
    float v = 0.f;
#pragma unroll
    for (int sl = 0; sl < 32; sl++) v += p[sl * 8192];
    const float scale = 1.0507009873554805f, alpha = 1.6732632423543772f;
    v = scale * (v > 0.f ? v : alpha * expm1f(v));
    float m = v;
    for (int off = 32; off; off >>= 1) m = fmaxf(m, __shfl_xor(m, off, 64));
    if ((tid & 63) == 0) r[wid] = m;
    __syncthreads();
    m = fmaxf(r[half * 2], r[half * 2 + 1]);
    float e = expf(v - m);
    float sum = e;
    for (int off = 32; off; off >>= 1) sum += __shfl_xor(sum, off, 64);
    if ((tid & 63) == 0) r2[wid] = sum;
    __syncthreads();
    sum = r2[half * 2] + r2[half * 2 + 1];
    out[(size_t)row * HID + f] = v - m - logf(sum);
  } else {
    __shared__ float ssb[4096];
    __shared__ float red[256];
    int b = blockIdx.x - 256;
    float loc = 0.f;
    for (int idx = tid; idx < 4096; idx += 256) {
      const float* p = part_ss + (size_t)b * 32 * 4096 + idx;
      float v = 0.f;
#pragma unroll
      for (int sl = 0; sl < 32; sl++) v += p[sl * 4096];
      ssb[idx] = v;
      loc += v * v;
    }
    red[tid] = loc; __syncthreads();
    for (int s2 = 128; s2; s2 >>= 1) { if (tid < s2) red[tid] += red[tid + s2]; __syncthreads(); }
    float fro = sqrtf(red[0]);
    __syncthreads();
    loc = 0.f;
    for (int i = tid; i < 4096; i += 256) {
      float v = ssb[i] / fro - (((i % 65) == 0) ? 0.125f : 0.f);
      loc += v * v;
    }
    red[tid] = loc; __syncthreads();
    for (int s2 = 128; s2; s2 >>= 1) { if (tid < s2) red[tid] += red[tid + s2]; __syncthreads(); }
    float ortho_b = sqrtf(red[0]);
    __syncthreads();
    loc = 0.f;
    if (tid < 64) { float v = ca[b * 64 + tid]; loc = v * v; }
    red[tid] = loc; __syncthreads();
    for (int s2 = 128; s2; s2 >>= 1) { if (tid < s2) red[tid] += red[tid + s2]; __syncthreads(); }
    float caSq = red[0];
    __syncthreads();
    loc = 0.f;
    if (tid < 64) { float v = ssum[b * 64 + tid]; loc = v * v; }
    red[tid] = loc; __syncthreads();
    for (int s2 = 128; s2; s2 >>= 1) { if (tid < s2) red[tid] += red[tid + s2]; __syncthreads(); }
    float ssumSq = red[0];
    __syncthreads();
    if (tid == 0) {
      float m2 = msum[b];                       // = 2*m
      float spectral_b = -(tr[b] - caSq / m2) / m2;
      float cluster_b = sqrtf(ssumSq) / 2048.0f * 8.0f - 1.0f;
      atomicAdd(&outs[0], (spectral_b + ortho_b + cluster_b) * 0.125f);
    }
  }
}

extern "C" void kernel_launch(void* const* d_in, const int* in_sizes, int n_in,
                              void* d_out, int out_size, void* d_ws, size_t ws_size,
                              hipStream_t stream) {
  (void)in_sizes; (void)n_in; (void)out_size; (void)ws_size;
  const float* x   = (const float*)d_in[0];
  const int* esrc  = (const int*)d_in[1];
  const int* edst  = (const int*)d_in[2];
  const float* W1  = (const float*)d_in[4];
  const float* b1  = (const float*)d_in[5];
  const float* W2  = (const float*)d_in[6];
  const float* b2  = (const float*)d_in[7];
  const float* Wp  = (const float*)d_in[8];
  const float* bp  = (const float*)d_in[9];
  float* out = (float*)d_out;
  float* ws  = (float*)d_ws;

  float* deg   = ws + OFF_DEG;
  float* agg1  = ws + OFF_AGG1;
  float* h1    = ws + OFF_H1;
  int*   nbr   = (int*)(ws + OFF_NBR);
  float* h2    = ws + OFF_H2;
  float* tr    = ws + OFF_TR;
  float* ca    = ws + OFF_CA;
  float* ssum  = ws + OFF_SSUM;
  float* msum  = ws + OFF_MS;
  float* part_pool = ws + OFF_H1;    // h1 dead after k_gemm2f
  float* part_ss   = ws + OFF_AGG2;
  float* s_out = out + 65537;   // chunk 2: s [8,2048,64]

  k_init<<<1093, 256, 0, stream>>>(ws, ws + OFF_TR, out + 65536);
  k_deg<<<NE / 256, 256, 0, stream>>>(edst, deg);
  k_scatter1<<<NE * 16 / 256, 256, 0, stream>>>(esrc, edst, x, deg, agg1);
  k_gemm1<<<NT, 128, 0, stream>>>(agg1, x, deg, W1, b1, h1);
  k_knn<<<dim3(64, 8), 1024, 0, stream>>>(h1, nbr);
  k_gemm2f<<<NT / 64, 256, 0, stream>>>(h1, nbr, W2, b2, h2);
  k_s<<<NT / 32, 256, 0, stream>>>(h2, Wp, bp, s_out);
  k_dmon_trace<<<768, 256, 0, stream>>>(s_out, h2, deg, part_pool, part_ss,
                                        ca, ssum, msum, esrc, edst, tr);
  k_final<<<264, 256, 0, stream>>>(part_pool, part_ss, ca, ssum, msum, tr,
                                   out, out + 65536);
}

// Round 12
// 236.854 us; speedup vs baseline: 1.0471x; 1.0027x over previous
//
#include <hip/hip_runtime.h>
#include <math.h>

#define BGR 8
#define NN 2048
#define KNN 4
#define INCH 16
#define HID 128
#define CL 64
#define NE 262144
#define NT (BGR*NN)   // 16384

// workspace layout (float offsets)
#define OFF_DEG   0            // 16384 (float deg)
#define OFF_AGG1  16384        // 262144
#define OFF_H1    278528       // 2097152  (reused as part_pool after gemm2f)
#define OFF_NBR   2375680      // 65536 (ints)
#define OFF_AGG2  2441216      // 2097152  (part_ss)
#define OFF_H2    4538368      // 2097152
#define OFF_TR    6733824      // 8
#define OFF_CA    6733832      // 512
#define OFF_SSUM  6734344      // 512
#define OFF_MS    6734856      // 8

// zero deg+agg1 (contiguous 278528) + tr/ca/ssum/msum (1040) + loss
__global__ void k_init(float* ws, float* small, float* loss) {
  int i = blockIdx.x * 256 + threadIdx.x;
  if (i < 278528) ws[i] = 0.f;
  int j = i - 278528;
  if (j >= 0 && j < 1040) small[j] = 0.f;
  if (i == 0) loss[0] = 0.f;
}

// in-degree histogram over original edges (also = adj.sum(1) for dmon)
__global__ void k_deg(const int* __restrict__ dst, float* __restrict__ deg) {
  int e = blockIdx.x * 256 + threadIdx.x;
  if (e < NE) atomicAdd(&deg[dst[e]], 1.0f);
}

// scatter x[src]*dis[src] into agg1[dst] (16 channels, linearity of GCN)
__global__ void k_scatter1(const int* __restrict__ src, const int* __restrict__ dst,
                           const float* __restrict__ x, const float* __restrict__ deg,
                           float* __restrict__ agg1) {
  int t = blockIdx.x * 256 + threadIdx.x;
  int e = t >> 4, c = t & 15;
  if (e >= NE) return;
  int s = src[e], d = dst[e];
  float ds = 1.0f / sqrtf(deg[s] + 1.0f);
  atomicAdd(&agg1[d * INCH + c], x[s * INCH + c] * ds);
}

// h1 = relu( ((agg1 + x*dis)*dis) @ W1 + b1 ); 16 nodes per 256-thread block
__global__ __launch_bounds__(256) void k_gemm1(const float* __restrict__ agg1,
    const float* __restrict__ x, const float* __restrict__ deg,
    const float* __restrict__ W1, const float* __restrict__ b1, float* __restrict__ h1) {
  __shared__ float a1[16][17];
  __shared__ float w[INCH * HID];   // 8KB
  int tid = threadIdx.x;
  for (int i = tid; i < INCH * HID / 4; i += 256) ((float4*)w)[i] = ((const float4*)W1)[i];
  int nl = tid >> 4, ch = tid & 15;
  int n = blockIdx.x * 16 + nl;
  float dn = 1.0f / sqrtf(deg[n] + 1.0f);
  a1[nl][ch] = (agg1[n * INCH + ch] + x[n * INCH + ch] * dn) * dn;
  __syncthreads();
  int j = tid & 127;
  int ng = (tid >> 7) * 8;   // 0 or 8
#pragma unroll
  for (int u = 0; u < 8; u++) {
    int node = ng + u;
    float s = b1[j];
#pragma unroll
    for (int c2 = 0; c2 < INCH; c2++) s += a1[node][c2] * w[c2 * HID + j];
    h1[(size_t)(blockIdx.x * 16 + node) * HID + j] = fmaxf(s, 0.f);
  }
}

// kNN k=4 per graph on h1[:, :3]. 1024-thread blocks, 2 rows/wave.
// Packed u32 keys (d2 bits | slot), 7-op min/max network; unroll-4 only
// (full unroll spills 25MB scratch — R7 post-mortem).
__global__ __launch_bounds__(1024) void k_knn(const float* __restrict__ h1, int* __restrict__ nbr) {
  __shared__ float4 c4[NN];   // 32KB
  int g = blockIdx.y, tid = threadIdx.x;
  for (int i = tid; i < NN; i += 1024)
    c4[i] = *(const float4*)(h1 + (size_t)(g * NN + i) * HID);
  __syncthreads();
  int wid = tid >> 6, lane = tid & 63;
  int row0 = blockIdx.x * 32 + wid * 2;
  float mx[2], my[2], mz[2];
#pragma unroll
  for (int r = 0; r < 2; r++) { float4 m = c4[row0 + r]; mx[r] = m.x; my[r] = m.y; mz[r] = m.z; }
  unsigned t0[2], t1[2], t2[2], t3[2];
#pragma unroll
  for (int r = 0; r < 2; r++) { t0[r] = t1[r] = t2[r] = t3[r] = 0xFFFFFFFFu; }
#pragma unroll 4
  for (int i = 0; i < 32; i++) {
    int j = i * 64 + lane;
    float4 p = c4[j];
#pragma unroll
    for (int r = 0; r < 2; r++) {
      float dx = p.x - mx[r], dy = p.y - my[r], dz = p.z - mz[r];
      float d2 = dx * dx + dy * dy + dz * dz;
      unsigned k = (__float_as_uint(d2) & 0xFFFFFFE0u) | (unsigned)i;
      if (j == row0 + r) k = 0xFFFFFFFFu;   // exclude self
      unsigned M0 = max(t0[r], k); t0[r] = min(t0[r], k);
      unsigned M1 = max(t1[r], M0); t1[r] = min(t1[r], M0);
      unsigned M2 = max(t2[r], M1); t2[r] = min(t2[r], M1);
      t3[r] = min(t3[r], M2);
    }
  }
#pragma unroll
  for (int r = 0; r < 2; r++) {
    unsigned a0 = t0[r], a1 = t1[r], a2 = t2[r], a3 = t3[r];
    int res[4];
#pragma unroll
    for (int k = 0; k < 4; k++) {
      int cj = (int)((a0 & 31u) << 6) | lane;
      unsigned wd = a0; int wj = cj;
#pragma unroll
      for (int off = 32; off; off >>= 1) {
        unsigned od = (unsigned)__shfl_xor((int)wd, off, 64);
        int oj = __shfl_xor(wj, off, 64);
        bool take = (od < wd) || (od == wd && oj < wj);
        wd = take ? od : wd; wj = take ? oj : wj;
      }
      res[k] = wj;
      bool pop = (cj == wj);
      a0 = pop ? a1 : a0; a1 = pop ? a2 : a1; a2 = pop ? a3 : a2;
      a3 = pop ? 0xFFFFFFFFu : a3;
    }
    if (lane == 0) {
      int node = g * NN + row0 + r;
      ((int4*)nbr)[node] = make_int4(g * NN + res[0], g * NN + res[1],
                                     g * NN + res[2], g * NN + res[3]);
    }
  }
}

// fused neighbor-gather + GEMM2: h2 = relu(((h1[n]+sum nbr h1)*0.2) @ W2 + b2)
__global__ __launch_bounds__(256) void k_gemm2f(const float* __restrict__ h1,
    const int* __restrict__ nbr, const float* __restrict__ W2,
    const float* __restrict__ b2, float* __restrict__ h2) {
  __shared__ float At[64][17];
  __shared__ float Bt[16 * 128];
  int tid = threadIdx.x;
  int rbase = blockIdx.x * 64;
  int r = tid >> 2, q = tid & 3;   // 4 threads per A-row, q = k-quad
  int4 nb = ((const int4*)nbr)[rbase + r];
  const float4* h4 = (const float4*)h1;
  size_t r0 = (size_t)(rbase + r) * 32, rx = (size_t)nb.x * 32, ry = (size_t)nb.y * 32,
         rz = (size_t)nb.z * 32, rw = (size_t)nb.w * 32;
  int rg = tid >> 5;            // 0..7 -> rows rg*8..+8
  int cg = (tid & 31) * 4;      // cols
  float acc[8][4];
#pragma unroll
  for (int i = 0; i < 8; i++)
#pragma unroll
    for (int j = 0; j < 4; j++) acc[i][j] = 0.f;
  for (int k0 = 0; k0 < HID; k0 += 16) {
    {
      int q4 = (k0 >> 2) + q;
      float4 a = h4[r0 + q4], bx = h4[rx + q4], by = h4[ry + q4],
             bz = h4[rz + q4], bw = h4[rw + q4];
      int kk = q * 4;
      At[r][kk]     = (a.x + bx.x + by.x + bz.x + bw.x) * 0.2f;
      At[r][kk + 1] = (a.y + bx.y + by.y + bz.y + bw.y) * 0.2f;
      At[r][kk + 2] = (a.z + bx.z + by.z + bz.z + bw.z) * 0.2f;
      At[r][kk + 3] = (a.w + bx.w + by.w + bz.w + bw.w) * 0.2f;
    }
    {
      int kk = tid >> 5;
      int cc = (tid & 31) * 4;
      *(float4*)&Bt[kk * 128 + cc] = *(const float4*)&W2[(k0 + kk) * HID + cc];
      *(float4*)&Bt[(kk + 8) * 128 + cc] = *(const float4*)&W2[(k0 + kk + 8) * HID + cc];
    }
    __syncthreads();
#pragma unroll
    for (int kk = 0; kk < 16; kk++) {
      float4 bv = *(const float4*)&Bt[kk * 128 + cg];
#pragma unroll
      for (int i = 0; i < 8; i++) {
        float av = At[rg * 8 + i][kk];
        acc[i][0] += av * bv.x; acc[i][1] += av * bv.y;
        acc[i][2] += av * bv.z; acc[i][3] += av * bv.w;
      }
    }
    __syncthreads();
  }
#pragma unroll
  for (int i = 0; i < 8; i++) {
    int rr = rbase + rg * 8 + i;
#pragma unroll
    for (int j = 0; j < 4; j++) {
      float v = acc[i][j] + b2[cg + j];
      h2[(size_t)rr * HID + cg + j] = fmaxf(v, 0.f);
    }
  }
}

// s = softmax(h2 @ Wp + bp) over C=64.
// Lane c register-caches Wp[:,c]; h2 row read as wave-uniform float4.
__global__ __launch_bounds__(256) void k_s(const float* __restrict__ h2,
    const float* __restrict__ Wp, const float* __restrict__ bp, float* __restrict__ s_out) {
  int tid = threadIdx.x, wid = tid >> 6, lane = tid & 63;
  float w[HID];
#pragma unroll
  for (int k = 0; k < HID; k++) w[k] = Wp[k * CL + lane];   // coalesced per k
  float bpv = bp[lane];
  int nbase = blockIdx.x * 32 + wid * 8;
  for (int u = 0; u < 8; u++) {
    int n = nbase + u;
    const float4* hp = (const float4*)(h2 + (size_t)n * HID);
    float acc = bpv;
#pragma unroll
    for (int k4 = 0; k4 < 32; k4++) {
      float4 h = hp[k4];
      acc += h.x * w[k4 * 4] + h.y * w[k4 * 4 + 1] + h.z * w[k4 * 4 + 2] + h.w * w[k4 * 4 + 3];
    }
    float m = acc;
    for (int off = 32; off; off >>= 1) m = fmaxf(m, __shfl_xor(m, off, 64));
    float e = expf(acc - m);
    float sum = e;
    for (int off = 32; off; off >>= 1) sum += __shfl_xor(sum, off, 64);
    s_out[(size_t)n * CL + lane] = e / sum;
  }
}

// fused: blocks 0..255 = DMoN tile reductions (pool/ss partials, plain
// stores; small ca/ssum/msum atomics); blocks 256..767 = edge trace.
__global__ __launch_bounds__(256) void k_dmon_trace(const float* __restrict__ s,
    const float* __restrict__ h2, const float* __restrict__ deg,
    float* __restrict__ part_pool, float* __restrict__ part_ss,
    float* __restrict__ ca, float* __restrict__ ssum, float* __restrict__ msum,
    const int* __restrict__ src, const int* __restrict__ dst, float* __restrict__ tr) {
  __shared__ float st[64 * 64];    // 16KB
  __shared__ float ht[64 * 128];   // 32KB
  __shared__ float dt[64];
  __shared__ float red[256];
  __shared__ float bins[8];
  int tid = threadIdx.x;
  if (blockIdx.x < 256) {
    int b = blockIdx.x >> 5, sl = blockIdx.x & 31;
    int nb = sl * 64;
    const float* sp = s + ((size_t)b * NN + nb) * CL;
    const float* hp = h2 + ((size_t)b * NN + nb) * HID;
    for (int i = tid; i < 64 * 64 / 4; i += 256) ((float4*)st)[i] = ((const float4*)sp)[i];
    for (int i = tid; i < 64 * 128 / 4; i += 256) ((float4*)ht)[i] = ((const float4*)hp)[i];
    if (tid < 64) dt[tid] = deg[b * NN + nb + tid];
    __syncthreads();
    int c = tid & 63;
    int fg = (tid >> 6) * 32;
    float acc[32];
#pragma unroll
    for (int i = 0; i < 32; i++) acc[i] = 0.f;
    for (int n = 0; n < 64; n++) {
      float a = st[n * 64 + c];
#pragma unroll
      for (int i = 0; i < 32; i++) acc[i] += a * ht[n * 128 + fg + i];
    }
    float* pp = part_pool + ((size_t)(b * 32 + sl)) * 8192 + c * 128 + fg;
#pragma unroll
    for (int i = 0; i < 32; i += 4)
      *(float4*)&pp[i] = make_float4(acc[i], acc[i + 1], acc[i + 2], acc[i + 3]);
    int dg = (tid >> 6) * 16;
    float sacc[16];
#pragma unroll
    for (int i = 0; i < 16; i++) sacc[i] = 0.f;
    for (int n = 0; n < 64; n++) {
      float a = st[n * 64 + c];
#pragma unroll
      for (int i = 0; i < 16; i++) sacc[i] += a * st[n * 64 + dg + i];
    }
    float* ps = part_ss + ((size_t)(b * 32 + sl)) * 4096 + c * 64 + dg;
#pragma unroll
    for (int i = 0; i < 16; i += 4)
      *(float4*)&ps[i] = make_float4(sacc[i], sacc[i + 1], sacc[i + 2], sacc[i + 3]);
    int q = tid >> 6;
    float a_ss = 0, a_ca = 0, a_m = 0;
    for (int n = q; n < 64; n += 4) {
      float sv = st[n * 64 + c];
      float dv = dt[n];
      a_ss += sv; a_ca += sv * dv;
      if (c == 0) a_m += dv;
    }
    red[tid] = a_ss; __syncthreads();
    if (q == 0) atomicAdd(&ssum[b * CL + c], red[c] + red[64 + c] + red[128 + c] + red[192 + c]);
    __syncthreads();
    red[tid] = a_ca; __syncthreads();
    if (q == 0) atomicAdd(&ca[b * CL + c], red[c] + red[64 + c] + red[128 + c] + red[192 + c]);
    __syncthreads();
    red[tid] = (c == 0) ? a_m : 0.f; __syncthreads();
    if (tid == 0) atomicAdd(&msum[b], red[0] + red[64] + red[128] + red[192]);
  } else {
    if (tid < 8) bins[tid] = 0.f;
    __syncthreads();
    int sub = tid & 15;
    int grp = ((blockIdx.x - 256) * 256 + tid) >> 4;   // 8192 groups
    const float4* s4 = (const float4*)s;
    for (int e = grp; e < NE; e += 8192) {
      int se = src[e], de = dst[e];
      float4 a = s4[se * 16 + sub];
      float4 b = s4[de * 16 + sub];
      float v = a.x * b.x + a.y * b.y + a.z * b.z + a.w * b.w;
      v += __shfl_xor(v, 1, 64);
      v += __shfl_xor(v, 2, 64);
      v += __shfl_xor(v, 4, 64);
      v += __shfl_xor(v, 8, 64);
      if (sub == 0) atomicAdd(&bins[se >> 11], v);
    }
    __syncthreads();
    if (tid < 8) atomicAdd(&tr[tid], bins[tid]);
  }
}

// fused epilogue: blocks 0..255 = pool-fold + selu + log_softmax (2 rows/blk);
// blocks 256..263 = per-graph scalar loss.
__global__ __launch_bounds__(256) void k_final(const float* __restrict__ part_pool,
    const float* __restrict__ part_ss, const float* __restrict__ ca,
    const float* __restrict__ ssum, const float* __restrict__ msum,
    const float* __restrict__ tr, float* __restrict__ out, float* __restrict__ outs) {
  int tid = threadIdx.x;
  if (blockIdx.x < 256) {
    __shared__ float r[4], r2[4];
    int half = tid >> 7, f = tid & 127;
    int row = blockIdx.x * 2 + half;
    int wid = tid >> 6;
    const float* p = part_pool + (size_t)(row >> 6) * 32 * 8192 + (row & 63) * 128 + f;
    float v = 0.f;
#pragma unroll
    for (int sl = 0; sl < 32; sl++) v += p[sl * 8192];
    const float scale = 1.0507009873554805f, alpha = 1.6732632423543772f;
    v = scale * (v > 0.f ? v : alpha * expm1f(v));
    float m = v;
    for (int off = 32; off; off >>= 1) m = fmaxf(m, __shfl_xor(m, off, 64));
    if ((tid & 63) == 0) r[wid] = m;
    __syncthreads();
    m = fmaxf(r[half * 2], r[half * 2 + 1]);
    float e = expf(v - m);
    float sum = e;
    for (int off = 32; off; off >>= 1) sum += __shfl_xor(sum, off, 64);
    if ((tid & 63) == 0) r2[wid] = sum;
    __syncthreads();
    sum = r2[half * 2] + r2[half * 2 + 1];
    out[(size_t)row * HID + f] = v - m - logf(sum);
  } else {
    __shared__ float ssb[4096];
    __shared__ float red[256];
    int b = blockIdx.x - 256;
    float loc = 0.f;
    for (int idx = tid; idx < 4096; idx += 256) {
      const float* p = part_ss + (size_t)b * 32 * 4096 + idx;
      float v = 0.f;
#pragma unroll
      for (int sl = 0; sl < 32; sl++) v += p[sl * 4096];
      ssb[idx] = v;
      loc += v * v;
    }
    red[tid] = loc; __syncthreads();
    for (int s2 = 128; s2; s2 >>= 1) { if (tid < s2) red[tid] += red[tid + s2]; __syncthreads(); }
    float fro = sqrtf(red[0]);
    __syncthreads();
    loc = 0.f;
    for (int i = tid; i < 4096; i += 256) {
      float v = ssb[i] / fro - (((i % 65) == 0) ? 0.125f : 0.f);
      loc += v * v;
    }
    red[tid] = loc; __syncthreads();
    for (int s2 = 128; s2; s2 >>= 1) { if (tid < s2) red[tid] += red[tid + s2]; __syncthreads(); }
    float ortho_b = sqrtf(red[0]);
    __syncthreads();
    loc = 0.f;
    if (tid < 64) { float v = ca[b * 64 + tid]; loc = v * v; }
    red[tid] = loc; __syncthreads();
    for (int s2 = 128; s2; s2 >>= 1) { if (tid < s2) red[tid] += red[tid + s2]; __syncthreads(); }
    float caSq = red[0];
    __syncthreads();
    loc = 0.f;
    if (tid < 64) { float v = ssum[b * 64 + tid]; loc = v * v; }
    red[tid] = loc; __syncthreads();
    for (int s2 = 128; s2; s2 >>= 1) { if (tid < s2) red[tid] += red[tid + s2]; __syncthreads(); }
    float ssumSq = red[0];
    __syncthreads();
    if (tid == 0) {
      float m2 = msum[b];                       // = 2*m
      float spectral_b = -(tr[b] - caSq / m2) / m2;
      float cluster_b = sqrtf(ssumSq) / 2048.0f * 8.0f - 1.0f;
      atomicAdd(&outs[0], (spectral_b + ortho_b + cluster_b) * 0.125f);
    }
  }
}

extern "C" void kernel_launch(void* const* d_in, const int* in_sizes, int n_in,
                              void* d_out, int out_size, void* d_ws, size_t ws_size,
                              hipStream_t stream) {
  (void)in_sizes; (void)n_in; (void)out_size; (void)ws_size;
  const float* x   = (const float*)d_in[0];
  const int* esrc  = (const int*)d_in[1];
  const int* edst  = (const int*)d_in[2];
  const float* W1  = (const float*)d_in[4];
  const float* b1  = (const float*)d_in[5];
  const float* W2  = (const float*)d_in[6];
  const float* b2  = (const float*)d_in[7];
  const float* Wp  = (const float*)d_in[8];
  const float* bp  = (const float*)d_in[9];
  float* out = (float*)d_out;
  float* ws  = (float*)d_ws;

  float* deg   = ws + OFF_DEG;
  float* agg1  = ws + OFF_AGG1;
  float* h1    = ws + OFF_H1;
  int*   nbr   = (int*)(ws + OFF_NBR);
  float* h2    = ws + OFF_H2;
  float* tr    = ws + OFF_TR;
  float* ca    = ws + OFF_CA;
  float* ssum  = ws + OFF_SSUM;
  float* msum  = ws + OFF_MS;
  float* part_pool = ws + OFF_H1;    // h1 dead after k_gemm2f
  float* part_ss   = ws + OFF_AGG2;
  float* s_out = out + 65537;   // chunk 2: s [8,2048,64]

  k_init<<<1093, 256, 0, stream>>>(ws, ws + OFF_TR, out + 65536);
  k_deg<<<NE / 256, 256, 0, stream>>>(edst, deg);
  k_scatter1<<<NE * 16 / 256, 256, 0, stream>>>(esrc, edst, x, deg, agg1);
  k_gemm1<<<NT / 16, 256, 0, stream>>>(agg1, x, deg, W1, b1, h1);
  k_knn<<<dim3(64, 8), 1024, 0, stream>>>(h1, nbr);
  k_gemm2f<<<NT / 64, 256, 0, stream>>>(h1, nbr, W2, b2, h2);
  k_s<<<NT / 32, 256, 0, stream>>>(h2, Wp, bp, s_out);
  k_dmon_trace<<<768, 256, 0, stream>>>(s_out, h2, deg, part_pool, part_ss,
                                        ca, ssum, msum, esrc, edst, tr);
  k_final<<<264, 256, 0, stream>>>(part_pool, part_ss, ca, ssum, msum, tr,
                                   out, out + 65536);
}